// Round 5
// baseline (1160.339 us; speedup 1.0000x reference)
//
#include <hip/hip_runtime.h>
#include <hip/hip_bf16.h>

// ---------------------------------------------------------------------------
// Longformer-style forward: B=2, S=4096, HID=768, L=4, H=12, D=64, W=128
// R11: R10's lean 512-thr/8-wave 128x128 GEMM (36 VGPR, occupancy-proven)
//      + T4 counted-vmcnt double-buffer: 64KB LDS (2 buf), stage(k+1) issued
//      before compute(k), s_waitcnt vmcnt(4) so next tile's loads stay in
//      flight across the barrier (drain 0 only on last tile). 2 blocks/CU
//      retained. (R9 showed this loop shape is correct; it failed only on
//      occupancy, which R10's decomposition fixed.)
// ---------------------------------------------------------------------------

typedef __bf16 bf16;
typedef bf16  bf16x8  __attribute__((ext_vector_type(8)));
typedef float floatx4 __attribute__((ext_vector_type(4)));

#define MFMA16(a, b, c) __builtin_amdgcn_mfma_f32_16x16x32_bf16((a), (b), (c), 0, 0, 0)

#define BARR() __builtin_amdgcn_s_barrier()
#define VMC4() asm volatile("s_waitcnt vmcnt(4)" ::: "memory")
#define VMC0() asm volatile("s_waitcnt vmcnt(0)" ::: "memory")

__device__ __forceinline__ void gld_lds16(const bf16* gp, bf16* lp) {
  __builtin_amdgcn_global_load_lds(
      (const __attribute__((address_space(1))) void*)gp,
      (__attribute__((address_space(3))) void*)lp, 16, 0, 0);
}

__device__ __forceinline__ float fast_rcp(float x) {
  return __builtin_amdgcn_rcpf(x);
}

// gelu(v) = v * sigmoid(1.59576912 v + 0.07135481 v^3)  (tanh form, folded)
__device__ __forceinline__ float gelu_fast(float v) {
  float x2 = v * v;
  float u = __builtin_fmaf(x2, -0.07135481f, -1.59576912f);
  float e = __expf(v * u);                 // exp(-2t)
  return v * fast_rcp(1.f + e);
}

// ------------------------- workspace layout (bytes) ------------------------
static constexpr size_t SZ_WTQKV = (size_t)4 * 2304 * 768 * 2;
static constexpr size_t SZ_WTO   = (size_t)4 * 768 * 768 * 2;
static constexpr size_t SZ_WTI   = (size_t)4 * 3072 * 768 * 2;
static constexpr size_t SZ_WTF   = (size_t)4 * 768 * 3072 * 2;
static constexpr size_t SZ_BQKV  = (size_t)4 * 2304 * 4;
static constexpr size_t SZ_H32   = (size_t)8192 * 768 * 4;
static constexpr size_t SZ_HBF   = (size_t)8192 * 768 * 2;
static constexpr size_t SZ_QKV   = (size_t)8192 * 2304 * 2;
static constexpr size_t SZ_ATTN  = (size_t)8192 * 768 * 2;
static constexpr size_t SZ_TMP   = (size_t)8192 * 768 * 4;   // also holds Vt (12.6MB)

static constexpr size_t OFF_WTQKV = 0;
static constexpr size_t OFF_WTO   = OFF_WTQKV + SZ_WTQKV;
static constexpr size_t OFF_WTI   = OFF_WTO   + SZ_WTO;
static constexpr size_t OFF_WTF   = OFF_WTI   + SZ_WTI;
static constexpr size_t OFF_BQKV  = OFF_WTF   + SZ_WTF;
static constexpr size_t OFF_H32   = OFF_BQKV  + SZ_BQKV;
static constexpr size_t OFF_HBF   = OFF_H32   + SZ_H32;
static constexpr size_t OFF_QKV   = OFF_HBF   + SZ_HBF;
static constexpr size_t OFF_ATTN  = OFF_QKV   + SZ_QKV;
static constexpr size_t OFF_TMP   = OFF_ATTN  + SZ_ATTN;
static constexpr size_t OFF_FFN1  = OFF_TMP   + SZ_TMP;

// ------------------------- weight transpose + cast -------------------------
__global__ __launch_bounds__(256) void transpose_cast(
    const float* __restrict__ src, bf16* __restrict__ dst,
    int K, int N, long sStride, long dStride) {
  __shared__ float tile[32][33];
  const int l = blockIdx.z;
  src += (long)l * sStride;
  dst += (long)l * dStride;
  const int n0 = blockIdx.x * 32, k0 = blockIdx.y * 32;
  const int tx = threadIdx.x, ty = threadIdx.y; // (32,8)
#pragma unroll
  for (int i = 0; i < 4; ++i)
    tile[ty + i * 8][tx] = src[(long)(k0 + ty + i * 8) * N + n0 + tx];
  __syncthreads();
#pragma unroll
  for (int i = 0; i < 4; ++i)
    dst[(long)(n0 + ty + i * 8) * K + k0 + tx] = (bf16)tile[tx][ty + i * 8];
}

__global__ void bias_concat(const float* __restrict__ bq, const float* __restrict__ bk,
                            const float* __restrict__ bv, float* __restrict__ bqkv) {
  int i = blockIdx.x * 256 + threadIdx.x; // 4*2304
  if (i >= 4 * 2304) return;
  int l = i / 2304, p = i % 2304;
  float v = (p < 768) ? bq[l * 768 + p]
          : (p < 1536) ? bk[l * 768 + p - 768] : bv[l * 768 + p - 1536];
  bqkv[i] = v;
}

// ------------------------------ LN helpers ---------------------------------
__device__ __forceinline__ void block_stats(float s1, float s2, float* red,
                                            float& mean, float& inv) {
  const int lane = threadIdx.x & 63, wave = threadIdx.x >> 6;
#pragma unroll
  for (int off = 32; off > 0; off >>= 1) {
    s1 += __shfl_down(s1, off, 64);
    s2 += __shfl_down(s2, off, 64);
  }
  if (lane == 0) { red[wave] = s1; red[4 + wave] = s2; }
  __syncthreads();
  s1 = red[0] + red[1] + red[2] + red[3];
  s2 = red[4] + red[5] + red[6] + red[7];
  mean = s1 * (1.f / 768.f);
  float var = s2 * (1.f / 768.f) - mean * mean;
  inv = rsqrtf(var + 1e-12f);
}

__global__ __launch_bounds__(256) void embed_ln_kernel(
    const float* __restrict__ emb, const float* __restrict__ pos,
    const float* __restrict__ tok, const float* __restrict__ g,
    const float* __restrict__ bta, float* __restrict__ h32, bf16* __restrict__ hbf) {
  __shared__ float red[8];
  const long base = (long)blockIdx.x * 768;
  const int s = blockIdx.x & 4095;
  const int t = threadIdx.x;
  float x[3], s1 = 0.f, s2 = 0.f;
#pragma unroll
  for (int i = 0; i < 3; ++i) {
    int c = t + i * 256;
    float v = emb[base + c] + pos[(long)(s + 1) * 768 + c] + tok[c];
    x[i] = v; s1 += v; s2 += v * v;
  }
  float mean, inv;
  block_stats(s1, s2, red, mean, inv);
#pragma unroll
  for (int i = 0; i < 3; ++i) {
    int c = t + i * 256;
    float y = (x[i] - mean) * inv * g[c] + bta[c];
    h32[base + c] = y;
    hbf[base + c] = (bf16)y;
  }
}

// h = LN(h32 + p0 + p1 + bias); p0/p1 are bf16 split-K partials.
__global__ __launch_bounds__(256) void add_ln_kernel(
    float* __restrict__ h32, const bf16* __restrict__ p0,
    const bf16* __restrict__ p1, const float* __restrict__ bias,
    const float* __restrict__ g, const float* __restrict__ bta,
    bf16* __restrict__ hbf) {
  __shared__ float red[8];
  const long base = (long)blockIdx.x * 768;
  const int t = threadIdx.x;
  float x[3], s1 = 0.f, s2 = 0.f;
#pragma unroll
  for (int i = 0; i < 3; ++i) {
    int c = t + i * 256;
    float v = h32[base + c] + (float)p0[base + c] + (float)p1[base + c] + bias[c];
    x[i] = v; s1 += v; s2 += v * v;
  }
  float mean, inv;
  block_stats(s1, s2, red, mean, inv);
#pragma unroll
  for (int i = 0; i < 3; ++i) {
    int c = t + i * 256;
    float y = (x[i] - mean) * inv * g[c] + bta[c];
    h32[base + c] = y;
    hbf[base + c] = (bf16)y;
  }
}

// ------------------------------- GEMM --------------------------------------
// 128x128 tile, BK=64, 512 thr = 8 waves (2M x 4N), per-wave 64x32 output
// (acc = 32 VGPR). 64KB LDS double-buffer + counted vmcnt:
//   prologue: stage tile0 -> buf0  (4 loads/thread)
//   iter kt:  stage tile kt+1 -> buf^1 ; s_waitcnt vmcnt(4)  [tile kt landed,
//             kt+1's 4 loads stay in flight] ; s_barrier ; MFMA from buf ;
//             s_barrier
// XOR chunk swizzle (chunk ^= row&7). launch_bounds(512,4): VGPR<=128.
// Block-cooperative epilogue: acc -> 64x136 LDS half -> 128B row stores.
// MODE: 0 = bf16 partial (split-K via z, no bias), 1 = bf16+bias, 2 = +GELU.
template <int MODE, int N, int LD>
__global__ __launch_bounds__(512, 4) void gemm_kernel(
    const bf16* __restrict__ A, const bf16* __restrict__ BT,
    const float* __restrict__ bias, void* __restrict__ C0, void* __restrict__ C1,
    int ksize) {
  __shared__ bf16 smem[32768];      // [buf][As 8192 | Bs 8192], 2 bufs = 64KB
  const int tid  = threadIdx.x;
  const int wave = tid >> 6, lane = tid & 63, l15 = lane & 15, quad = lane >> 4;
  const int wm = wave >> 2, wn = wave & 3;   // 2M x 4N
  const long m0 = (long)blockIdx.x * 128;
  const int  n0 = blockIdx.y * 128;
  const int  k0 = blockIdx.z * ksize;

  floatx4 acc[4][2] = {};
  const int rowoff = tid >> 3;                  // 0..63
  const int sc_sw = (tid & 7) ^ (rowoff & 7);   // swizzled global chunk
  const int fsw = l15 & 7;                      // frag-read swizzle key
  const bf16* Ag = A + m0 * LD + k0 + sc_sw * 8;
  const bf16* Bg = BT + (long)n0 * LD + k0 + sc_sw * 8;
  const int nk = ksize >> 6;

  // prologue: stage tile 0 into buf 0
#pragma unroll
  for (int p = 0; p < 2; ++p) {
    const int row = p * 64 + rowoff;
    gld_lds16(Ag + (long)row * LD, smem + p * 4096 + wave * 512);
    gld_lds16(Bg + (long)row * LD, smem + 8192 + p * 4096 + wave * 512);
  }

  for (int kt = 0; kt < nk; ++kt) {
    const int cur = kt & 1;
    if (kt + 1 < nk) {
      bf16* nb = smem + (cur ^ 1) * 16384;
      const int off = (kt + 1) * 64;
#pragma unroll
      for (int p = 0; p < 2; ++p) {
        const int row = p * 64 + rowoff;
        gld_lds16(Ag + (long)row * LD + off, nb + p * 4096 + wave * 512);
        gld_lds16(Bg + (long)row * LD + off, nb + 8192 + p * 4096 + wave * 512);
      }
      VMC4();
    } else {
      VMC0();
    }
    BARR();
    const bf16* As = smem + cur * 16384;
    const bf16* Bs = As + 8192;
#pragma unroll
    for (int kk = 0; kk < 2; ++kk) {
      const int ch = ((kk * 4 + quad) ^ fsw) * 8;  // swizzled chunk offset
      bf16x8 af[4], bfr[2];
#pragma unroll
      for (int nt = 0; nt < 2; ++nt)
        bfr[nt] = *(const bf16x8*)&Bs[(wn * 32 + nt * 16 + l15) * 64 + ch];
#pragma unroll
      for (int mt = 0; mt < 4; ++mt)
        af[mt] = *(const bf16x8*)&As[(wm * 64 + mt * 16 + l15) * 64 + ch];
#pragma unroll
      for (int mt = 0; mt < 4; ++mt)
#pragma unroll
        for (int nt = 0; nt < 2; ++nt)
          acc[mt][nt] = MFMA16(af[mt], bfr[nt], acc[mt][nt]);
    }
    BARR();
  }

  // ---- block-cooperative epilogue: two 64-row halves via 64x136 LDS ----
  bf16* Cg = (bf16*)((MODE == 0 && blockIdx.z != 0) ? C1 : C0);
#pragma unroll
  for (int h = 0; h < 2; ++h) {
    if (wm == h) {
#pragma unroll
      for (int mt = 0; mt < 4; ++mt)
#pragma unroll
        for (int nt = 0; nt < 2; ++nt) {
          const float bb = (MODE == 0) ? 0.f : bias[n0 + wn * 32 + nt * 16 + l15];
#pragma unroll
          for (int r = 0; r < 4; ++r) {
            float v = acc[mt][nt][r] + bb;
            if (MODE == 2) v = gelu_fast(v);
            smem[(mt * 16 + quad * 4 + r) * 136 + wn * 32 + nt * 16 + l15] = (bf16)v;
          }
        }
    }
    __syncthreads();
    {
      const int row = tid >> 3;                    // 0..63
#pragma unroll
      for (int p = 0; p < 2; ++p) {
        const int chunk = (tid & 7) + p * 8;       // 0..15
        bf16x8 vv = *(const bf16x8*)&smem[row * 136 + chunk * 8];
        *(bf16x8*)&Cg[(m0 + h * 64 + row) * N + n0 + chunk * 8] = vv;
      }
    }
    __syncthreads();
  }
}

// -------------------- V transpose: qkv V-part -> Vt[b,h][d][S] -------------
__global__ __launch_bounds__(256) void vtrans_kernel(
    const bf16* __restrict__ qkv, bf16* __restrict__ vt) {
  __shared__ bf16 tile[64 * 68];
  const int s0 = blockIdx.x * 64, h = blockIdx.y, b = blockIdx.z;
  const int tid = threadIdx.x;
  const bf16* src = qkv + (long)b * 4096 * 2304 + 1536 + h * 64;
#pragma unroll
  for (int p = 0; p < 2; ++p) {
    const int i = p * 256 + tid;
    const int r = i >> 3, c = i & 7;
    *(uint4*)&tile[r * 68 + c * 8] = *(const uint4*)&src[(long)(s0 + r) * 2304 + c * 8];
  }
  __syncthreads();
  bf16* dst = vt + ((long)(b * 12 + h)) * 64 * 4096;
#pragma unroll
  for (int p = 0; p < 2; ++p) {
    const int i = p * 256 + tid;
    const int d = i >> 3, cs = i & 7;
    bf16 vals[8];
#pragma unroll
    for (int u = 0; u < 8; ++u) vals[u] = tile[(cs * 8 + u) * 68 + d];
    *(uint4*)&dst[(long)d * 4096 + s0 + cs * 8] = *(const uint4*)vals;
  }
}

// ----------------------------- attention -----------------------------------
__global__ __launch_bounds__(256) void attn_kernel(
    const bf16* __restrict__ qkv, const bf16* __restrict__ vt,
    const int* __restrict__ amask, bf16* __restrict__ attn_out) {
  constexpr int S = 4096, HID3 = 2304;
  __shared__ bf16 Ss[64 * 328];
  __shared__ bf16 Ts[64 * 64];
  __shared__ float redm[64], reds[64];

  const int x = blockIdx.x, q0 = x * 64, h = blockIdx.y, b = blockIdx.z;
  const int tid = threadIdx.x, wave = tid >> 6, lane = tid & 63;
  const int l15 = lane & 15, quad = lane >> 4;
  const int rowoff = tid >> 3;
  const int sc_sw = (tid & 7) ^ (rowoff & 7);
  const int fsw = l15 & 7;
  const int t_lo = (x < 2) ? (2 - x) : 0;
  const int t_hi = (x > 61) ? (66 - x) : 5;

  const bf16* Qb = qkv + (long)b * S * HID3 + h * 64;
  const bf16* Kb = Qb + 768;
  const bf16* Vt_bh = vt + ((long)(b * 12 + h)) * 64 * 4096;

  bf16x8 qf[2];
  {
    const long qrow = q0 + wave * 16 + l15;
    qf[0] = *(const bf16x8*)&Qb[qrow * HID3 + quad * 8];
    qf[1] = *(const bf16x8*)&Qb[qrow * HID3 + 32 + quad * 8];
  }

  float mrow[4] = {-3e38f, -3e38f, -3e38f, -3e38f};

  // ---- Phase A: scores ----
  for (int t = t_lo; t < t_hi; ++t) {
    const int j0 = (x - 2 + t) * 64;
    __syncthreads();
#pragma unroll
    for (int p = 0; p < 2; ++p) {
      const int key = p * 32 + rowoff;
      gld_lds16(Kb + (long)(j0 + key) * HID3 + sc_sw * 8, &Ts[p * 2048 + wave * 512]);
    }
    __syncthreads();
    floatx4 sacc[4] = {};
#pragma unroll
    for (int kk = 0; kk < 2; ++kk) {
      const int ch = ((kk * 4 + quad) ^ fsw) * 8;
#pragma unroll
      for (int nt = 0; nt < 4; ++nt) {
        bf16x8 kf = *(const bf16x8*)&Ts[(nt * 16 + l15) * 64 + ch];
        sacc[nt] = MFMA16(qf[kk], kf, sacc[nt]);
      }
    }
#pragma unroll
    for (int nt = 0; nt < 4; ++nt) {
      const int jj = t * 64 + nt * 16 + l15;
      const int j = j0 + nt * 16 + l15;
      const bool jv = (amask[b * S + j] != 0);
#pragma unroll
      for (int r = 0; r < 4; ++r) {
        const int qi = wave * 16 + quad * 4 + r;
        const bool ok = jv && (jj >= qi) && (jj <= qi + 256);
        const float sv = ok ? sacc[nt][r] * 0.125f : -1e9f;
        mrow[r] = fmaxf(mrow[r], sv);
        Ss[(wave * 16 + quad * 4 + r) * 328 + jj] = (bf16)sv;
      }
    }
  }
#pragma unroll
  for (int off = 1; off < 16; off <<= 1)
#pragma unroll
    for (int r = 0; r < 4; ++r)
      mrow[r] = fmaxf(mrow[r], __shfl_xor(mrow[r], off, 64));
  if (l15 == 0) {
#pragma unroll
    for (int r = 0; r < 4; ++r) redm[wave * 16 + quad * 4 + r] = mrow[r];
  }
  __syncthreads();

  // ---- Phase B: softmax pass (rows re-owned by l15, chunks by quad) ----
  {
    const int row = wave * 16 + l15;
    const float mx = redm[row];
    float sum = 0.f;
    for (int c = t_lo * 8 + quad; c < t_hi * 8; c += 4) {
      bf16x8 pv = *(const bf16x8*)&Ss[row * 328 + c * 8];
#pragma unroll
      for (int u = 0; u < 8; ++u) {
        const float p = __expf((float)pv[u] - mx);
        sum += p;
        pv[u] = (bf16)p;
      }
      *(bf16x8*)&Ss[row * 328 + c * 8] = pv;
    }
    sum += __shfl_xor(sum, 16, 64);
    sum += __shfl_xor(sum, 32, 64);
    if (quad == 0) reds[row] = sum;
  }
  __syncthreads();

  // ---- Phase C: P @ V with pre-transposed V ----
  floatx4 oacc[4] = {};
  for (int t = t_lo; t < t_hi; ++t) {
    const int j0 = (x - 2 + t) * 64;
    __syncthreads();
#pragma unroll
    for (int p = 0; p < 2; ++p) {
      const int d = p * 32 + rowoff;
      gld_lds16(Vt_bh + (long)d * 4096 + j0 + sc_sw * 8, &Ts[p * 2048 + wave * 512]);
    }
    __syncthreads();
#pragma unroll
    for (int kk = 0; kk < 2; ++kk) {
      const int ko = kk * 32 + quad * 8;
      const int ch = ((kk * 4 + quad) ^ fsw) * 8;
      bf16x8 pf = *(const bf16x8*)&Ss[(wave * 16 + l15) * 328 + t * 64 + ko];
#pragma unroll
      for (int nt = 0; nt < 4; ++nt) {
        bf16x8 vf = *(const bf16x8*)&Ts[(nt * 16 + l15) * 64 + ch];
        oacc[nt] = MFMA16(pf, vf, oacc[nt]);
      }
    }
  }

  float inv[4];
#pragma unroll
  for (int r = 0; r < 4; ++r) inv[r] = fast_rcp(reds[wave * 16 + quad * 4 + r]);
  const long orow = (long)b * S + q0 + wave * 16 + quad * 4;
#pragma unroll
  for (int nt = 0; nt < 4; ++nt)
#pragma unroll
    for (int r = 0; r < 4; ++r)
      attn_out[(orow + r) * 768 + h * 64 + nt * 16 + l15] =
          (bf16)(oacc[nt][r] * inv[r]);
}

// ------------------------------ final head ---------------------------------
__global__ __launch_bounds__(256) void final_kernel(
    const float* __restrict__ h32, const float* __restrict__ Wp,
    const float* __restrict__ bp, float* __restrict__ out) {
  const int wave = threadIdx.x >> 6, lane = threadIdx.x & 63;
  const long tok = (long)blockIdx.x * 4 + wave;
  float s = 0.f;
#pragma unroll
  for (int i = 0; i < 12; ++i) {
    const int c = lane + i * 64;
    s += h32[tok * 768 + c] * Wp[c];
  }
#pragma unroll
  for (int off = 32; off > 0; off >>= 1) s += __shfl_down(s, off, 64);
  if (lane == 0) out[tok] = fast_rcp(1.f + __expf(-(s + bp[0])));
}

// ------------------------------ launcher -----------------------------------
extern "C" void kernel_launch(void* const* d_in, const int* in_sizes, int n_in,
                              void* d_out, int out_size, void* d_ws, size_t ws_size,
                              hipStream_t stream) {
  const float* emb   = (const float*)d_in[0];
  const int*   amask = (const int*)d_in[1];
  const float* pos   = (const float*)d_in[2];
  const float* tok   = (const float*)d_in[3];
  const float* elng  = (const float*)d_in[4];
  const float* elnb  = (const float*)d_in[5];
  const float* Wq = (const float*)d_in[6];   const float* bq = (const float*)d_in[7];
  const float* Wk = (const float*)d_in[8];   const float* bk = (const float*)d_in[9];
  const float* Wv = (const float*)d_in[10];  const float* bv = (const float*)d_in[11];
  const float* Wo = (const float*)d_in[12];  const float* bo = (const float*)d_in[13];
  const float* ln1g = (const float*)d_in[14]; const float* ln1b = (const float*)d_in[15];
  const float* Wi = (const float*)d_in[16];  const float* bi = (const float*)d_in[17];
  const float* Wf = (const float*)d_in[18];  const float* bfb = (const float*)d_in[19];
  const float* ln2g = (const float*)d_in[20]; const float* ln2b = (const float*)d_in[21];
  const float* Wp = (const float*)d_in[22];  const float* bp = (const float*)d_in[23];
  float* out = (float*)d_out;

  char* ws = (char*)d_ws;
  bf16*  WTqkv = (bf16*)(ws + OFF_WTQKV);
  bf16*  WTo   = (bf16*)(ws + OFF_WTO);
  bf16*  WTi   = (bf16*)(ws + OFF_WTI);
  bf16*  WTf   = (bf16*)(ws + OFF_WTF);
  float* bqkv  = (float*)(ws + OFF_BQKV);
  float* h32   = (float*)(ws + OFF_H32);
  bf16*  hbf   = (bf16*)(ws + OFF_HBF);
  bf16*  qkvb  = (bf16*)(ws + OFF_QKV);
  bf16*  part1 = (bf16*)(ws + OFF_QKV);    // bf16 overlay; qkvb dead after attn
  bf16*  attnb = (bf16*)(ws + OFF_ATTN);
  bf16*  part0 = (bf16*)(ws + OFF_TMP);
  bf16*  vtb   = (bf16*)(ws + OFF_TMP);    // Vt overlay; part0 dead during attn
  bf16*  ffn1  = (bf16*)(ws + OFF_FFN1);

  const dim3 tb(32, 8, 1);
  transpose_cast<<<dim3(24, 24, 4), tb, 0, stream>>>(Wq, WTqkv,               768, 768,  (long)768 * 768,  (long)2304 * 768);
  transpose_cast<<<dim3(24, 24, 4), tb, 0, stream>>>(Wk, WTqkv + 768 * 768,   768, 768,  (long)768 * 768,  (long)2304 * 768);
  transpose_cast<<<dim3(24, 24, 4), tb, 0, stream>>>(Wv, WTqkv + 1536 * 768,  768, 768,  (long)768 * 768,  (long)2304 * 768);
  transpose_cast<<<dim3(24, 24, 4), tb, 0, stream>>>(Wo, WTo,                 768, 768,  (long)768 * 768,  (long)768 * 768);
  transpose_cast<<<dim3(96, 24, 4), tb, 0, stream>>>(Wi, WTi,                 768, 3072, (long)768 * 3072, (long)3072 * 768);
  transpose_cast<<<dim3(24, 96, 4), tb, 0, stream>>>(Wf, WTf,                 3072, 768, (long)3072 * 768, (long)768 * 3072);
  bias_concat<<<36, 256, 0, stream>>>(bq, bk, bv, bqkv);

  embed_ln_kernel<<<8192, 256, 0, stream>>>(emb, pos, tok, elng, elnb, h32, hbf);

  for (int l = 0; l < 4; ++l) {
    gemm_kernel<1, 2304, 768><<<dim3(64, 18, 1), 512, 0, stream>>>(
        hbf, WTqkv + (size_t)l * 2304 * 768, bqkv + l * 2304, qkvb, nullptr, 768);
    vtrans_kernel<<<dim3(64, 12, 2), 256, 0, stream>>>(qkvb, vtb);
    attn_kernel<<<dim3(64, 12, 2), 256, 0, stream>>>(qkvb, vtb, amask, attnb);
    gemm_kernel<0, 768, 768><<<dim3(64, 6, 2), 512, 0, stream>>>(
        attnb, WTo + (size_t)l * 768 * 768, nullptr, part0, part1, 384);
    add_ln_kernel<<<8192, 256, 0, stream>>>(h32, part0, part1, bo + l * 768,
                                            ln1g + l * 768, ln1b + l * 768, hbf);
    gemm_kernel<2, 3072, 768><<<dim3(64, 24, 1), 512, 0, stream>>>(
        hbf, WTi + (size_t)l * 3072 * 768, bi + l * 3072, ffn1, nullptr, 768);
    gemm_kernel<0, 768, 3072><<<dim3(64, 6, 2), 512, 0, stream>>>(
        ffn1, WTf + (size_t)l * 768 * 3072, nullptr, part0, part1, 1536);
    add_ln_kernel<<<8192, 256, 0, stream>>>(h32, part0, part1, bfb + l * 768,
                                            ln2g + l * 768, ln2b + l * 768, hbf);
  }

  final_kernel<<<2048, 256, 0, stream>>>(h32, Wp, bp, out);
}

// Round 7
// 1087.632 us; speedup vs baseline: 1.0668x; 1.0668x over previous
//
#include <hip/hip_runtime.h>
#include <hip/hip_bf16.h>

// ---------------------------------------------------------------------------
// Longformer-style forward: B=2, S=4096, HID=768, L=4, H=12, D=64, W=128
// R12: R10 GEMM (proven best: 512thr/8wave 128x128, 32KB single-buffer,
//      occupancy ~55%) + V-transpose FUSED into QKV epilogue: for n0>=1536
//      tiles, each lane's acc[mt][nt][0..3] is 4 consecutive s at fixed d ->
//      direct 8B stores to vt[b,hd][d][s]. vtrans kernel deleted (~50us e2e).
// ---------------------------------------------------------------------------

typedef __bf16 bf16;
typedef bf16  bf16x4  __attribute__((ext_vector_type(4)));
typedef bf16  bf16x8  __attribute__((ext_vector_type(8)));
typedef float floatx4 __attribute__((ext_vector_type(4)));

#define MFMA16(a, b, c) __builtin_amdgcn_mfma_f32_16x16x32_bf16((a), (b), (c), 0, 0, 0)

__device__ __forceinline__ void gld_lds16(const bf16* gp, bf16* lp) {
  __builtin_amdgcn_global_load_lds(
      (const __attribute__((address_space(1))) void*)gp,
      (__attribute__((address_space(3))) void*)lp, 16, 0, 0);
}

__device__ __forceinline__ float fast_rcp(float x) {
  return __builtin_amdgcn_rcpf(x);
}

// gelu(v) = v * sigmoid(1.59576912 v + 0.07135481 v^3)  (tanh form, folded)
__device__ __forceinline__ float gelu_fast(float v) {
  float x2 = v * v;
  float u = __builtin_fmaf(x2, -0.07135481f, -1.59576912f);
  float e = __expf(v * u);                 // exp(-2t)
  return v * fast_rcp(1.f + e);
}

// ------------------------- workspace layout (bytes) ------------------------
static constexpr size_t SZ_WTQKV = (size_t)4 * 2304 * 768 * 2;
static constexpr size_t SZ_WTO   = (size_t)4 * 768 * 768 * 2;
static constexpr size_t SZ_WTI   = (size_t)4 * 3072 * 768 * 2;
static constexpr size_t SZ_WTF   = (size_t)4 * 768 * 3072 * 2;
static constexpr size_t SZ_BQKV  = (size_t)4 * 2304 * 4;
static constexpr size_t SZ_H32   = (size_t)8192 * 768 * 4;
static constexpr size_t SZ_HBF   = (size_t)8192 * 768 * 2;
static constexpr size_t SZ_QKV   = (size_t)8192 * 2304 * 2;
static constexpr size_t SZ_ATTN  = (size_t)8192 * 768 * 2;
static constexpr size_t SZ_TMP   = (size_t)8192 * 768 * 4;   // also holds Vt (12.6MB)

static constexpr size_t OFF_WTQKV = 0;
static constexpr size_t OFF_WTO   = OFF_WTQKV + SZ_WTQKV;
static constexpr size_t OFF_WTI   = OFF_WTO   + SZ_WTO;
static constexpr size_t OFF_WTF   = OFF_WTI   + SZ_WTI;
static constexpr size_t OFF_BQKV  = OFF_WTF   + SZ_WTF;
static constexpr size_t OFF_H32   = OFF_BQKV  + SZ_BQKV;
static constexpr size_t OFF_HBF   = OFF_H32   + SZ_H32;
static constexpr size_t OFF_QKV   = OFF_HBF   + SZ_HBF;
static constexpr size_t OFF_ATTN  = OFF_QKV   + SZ_QKV;
static constexpr size_t OFF_TMP   = OFF_ATTN  + SZ_ATTN;
static constexpr size_t OFF_FFN1  = OFF_TMP   + SZ_TMP;

// ------------------------- weight transpose + cast -------------------------
__global__ __launch_bounds__(256) void transpose_cast(
    const float* __restrict__ src, bf16* __restrict__ dst,
    int K, int N, long sStride, long dStride) {
  __shared__ float tile[32][33];
  const int l = blockIdx.z;
  src += (long)l * sStride;
  dst += (long)l * dStride;
  const int n0 = blockIdx.x * 32, k0 = blockIdx.y * 32;
  const int tx = threadIdx.x, ty = threadIdx.y; // (32,8)
#pragma unroll
  for (int i = 0; i < 4; ++i)
    tile[ty + i * 8][tx] = src[(long)(k0 + ty + i * 8) * N + n0 + tx];
  __syncthreads();
#pragma unroll
  for (int i = 0; i < 4; ++i)
    dst[(long)(n0 + ty + i * 8) * K + k0 + tx] = (bf16)tile[tx][ty + i * 8];
}

__global__ void bias_concat(const float* __restrict__ bq, const float* __restrict__ bk,
                            const float* __restrict__ bv, float* __restrict__ bqkv) {
  int i = blockIdx.x * 256 + threadIdx.x; // 4*2304
  if (i >= 4 * 2304) return;
  int l = i / 2304, p = i % 2304;
  float v = (p < 768) ? bq[l * 768 + p]
          : (p < 1536) ? bk[l * 768 + p - 768] : bv[l * 768 + p - 1536];
  bqkv[i] = v;
}

// ------------------------------ LN helpers ---------------------------------
__device__ __forceinline__ void block_stats(float s1, float s2, float* red,
                                            float& mean, float& inv) {
  const int lane = threadIdx.x & 63, wave = threadIdx.x >> 6;
#pragma unroll
  for (int off = 32; off > 0; off >>= 1) {
    s1 += __shfl_down(s1, off, 64);
    s2 += __shfl_down(s2, off, 64);
  }
  if (lane == 0) { red[wave] = s1; red[4 + wave] = s2; }
  __syncthreads();
  s1 = red[0] + red[1] + red[2] + red[3];
  s2 = red[4] + red[5] + red[6] + red[7];
  mean = s1 * (1.f / 768.f);
  float var = s2 * (1.f / 768.f) - mean * mean;
  inv = rsqrtf(var + 1e-12f);
}

__global__ __launch_bounds__(256) void embed_ln_kernel(
    const float* __restrict__ emb, const float* __restrict__ pos,
    const float* __restrict__ tok, const float* __restrict__ g,
    const float* __restrict__ bta, float* __restrict__ h32, bf16* __restrict__ hbf) {
  __shared__ float red[8];
  const long base = (long)blockIdx.x * 768;
  const int s = blockIdx.x & 4095;
  const int t = threadIdx.x;
  float x[3], s1 = 0.f, s2 = 0.f;
#pragma unroll
  for (int i = 0; i < 3; ++i) {
    int c = t + i * 256;
    float v = emb[base + c] + pos[(long)(s + 1) * 768 + c] + tok[c];
    x[i] = v; s1 += v; s2 += v * v;
  }
  float mean, inv;
  block_stats(s1, s2, red, mean, inv);
#pragma unroll
  for (int i = 0; i < 3; ++i) {
    int c = t + i * 256;
    float y = (x[i] - mean) * inv * g[c] + bta[c];
    h32[base + c] = y;
    hbf[base + c] = (bf16)y;
  }
}

// h = LN(h32 + p0 + p1 + bias); p0/p1 are bf16 split-K partials.
__global__ __launch_bounds__(256) void add_ln_kernel(
    float* __restrict__ h32, const bf16* __restrict__ p0,
    const bf16* __restrict__ p1, const float* __restrict__ bias,
    const float* __restrict__ g, const float* __restrict__ bta,
    bf16* __restrict__ hbf) {
  __shared__ float red[8];
  const long base = (long)blockIdx.x * 768;
  const int t = threadIdx.x;
  float x[3], s1 = 0.f, s2 = 0.f;
#pragma unroll
  for (int i = 0; i < 3; ++i) {
    int c = t + i * 256;
    float v = h32[base + c] + (float)p0[base + c] + (float)p1[base + c] + bias[c];
    x[i] = v; s1 += v; s2 += v * v;
  }
  float mean, inv;
  block_stats(s1, s2, red, mean, inv);
#pragma unroll
  for (int i = 0; i < 3; ++i) {
    int c = t + i * 256;
    float y = (x[i] - mean) * inv * g[c] + bta[c];
    h32[base + c] = y;
    hbf[base + c] = (bf16)y;
  }
}

// ------------------------------- GEMM --------------------------------------
// 128x128 tile, BK=64, 512 thr = 8 waves (2M x 4N), per-wave 64x32 output
// (acc = 32 VGPR). Single-buffered 32KB LDS, 2-barrier loop (stage ->
// sync -> compute -> sync). XOR chunk swizzle (chunk ^= row&7).
// launch_bounds(512,4): VGPR capped at 128 -> 16 waves/CU measured ~55% occ.
// Epilogue:
//   * Q/K & generic tiles: block-cooperative, acc -> 64x136 LDS half ->
//     128B coalesced row stores.
//   * QKV V-tiles (MODE 1, n0>=1536): fused transpose store. MFMA C-layout
//     gives each lane 4 consecutive m (=seq) at fixed n (=d): 8B runs
//     direct to vt[b*12+hd][d][s]. Replaces the vtrans kernel, bit-identical.
// MODE: 0 = bf16 partial (split-K via z, no bias), 1 = bf16+bias, 2 = +GELU.
template <int MODE, int N, int LD>
__global__ __launch_bounds__(512, 4) void gemm_kernel(
    const bf16* __restrict__ A, const bf16* __restrict__ BT,
    const float* __restrict__ bias, void* __restrict__ C0, void* __restrict__ C1,
    bf16* __restrict__ vtout, int ksize) {
  __shared__ bf16 smem[16384];      // As = [0,8192), Bs = [8192,16384)
  bf16* As = smem;
  bf16* Bs = smem + 8192;
  const int tid  = threadIdx.x;
  const int wave = tid >> 6, lane = tid & 63, l15 = lane & 15, quad = lane >> 4;
  const int wm = wave >> 2, wn = wave & 3;   // 2M x 4N
  const long m0 = (long)blockIdx.x * 128;
  const int  n0 = blockIdx.y * 128;
  const int  k0 = blockIdx.z * ksize;

  floatx4 acc[4][2] = {};
  const int rowoff = tid >> 3;                  // 0..63
  const int sc_sw = (tid & 7) ^ (rowoff & 7);   // swizzled global chunk
  const int fsw = l15 & 7;                      // frag-read swizzle key
  const bf16* Ag = A + m0 * LD + k0 + sc_sw * 8;
  const bf16* Bg = BT + (long)n0 * LD + k0 + sc_sw * 8;

  for (int kt = 0; kt < ksize; kt += 64) {
#pragma unroll
    for (int p = 0; p < 2; ++p) {
      const int row = p * 64 + rowoff;
      gld_lds16(Ag + (long)row * LD + kt, As + p * 4096 + wave * 512);
      gld_lds16(Bg + (long)row * LD + kt, Bs + p * 4096 + wave * 512);
    }
    __syncthreads();
#pragma unroll
    for (int kk = 0; kk < 2; ++kk) {
      const int ch = ((kk * 4 + quad) ^ fsw) * 8;  // swizzled chunk offset
      bf16x8 af[4], bfr[2];
#pragma unroll
      for (int nt = 0; nt < 2; ++nt)
        bfr[nt] = *(const bf16x8*)&Bs[(wn * 32 + nt * 16 + l15) * 64 + ch];
#pragma unroll
      for (int mt = 0; mt < 4; ++mt)
        af[mt] = *(const bf16x8*)&As[(wm * 64 + mt * 16 + l15) * 64 + ch];
#pragma unroll
      for (int mt = 0; mt < 4; ++mt)
#pragma unroll
        for (int nt = 0; nt < 2; ++nt)
          acc[mt][nt] = MFMA16(af[mt], bfr[nt], acc[mt][nt]);
    }
    __syncthreads();
  }

  // ---- fused V-transpose store (QKV gemm, V tiles) ----
  if (MODE == 1 && n0 >= 1536) {
    const int b = (int)(m0 >> 12);
    const int sbase = ((int)m0 & 4095) + wm * 64 + quad * 4;
#pragma unroll
    for (int nt = 0; nt < 2; ++nt) {
      const int ng = n0 + wn * 32 + nt * 16 + l15;   // global col in [1536,2304)
      const float bb = bias[ng];
      const int col = ng - 1536;                     // hd = col>>6, d = col&63
      bf16* dst = vtout + (((long)(b * 12 + (col >> 6)) * 64 + (col & 63)) << 12);
#pragma unroll
      for (int mt = 0; mt < 4; ++mt) {
        bf16x4 v4;
#pragma unroll
        for (int r = 0; r < 4; ++r) v4[r] = (bf16)(acc[mt][nt][r] + bb);
        *(bf16x4*)&dst[sbase + mt * 16] = v4;
      }
    }
    return;
  }

  // ---- block-cooperative epilogue: two 64-row halves via 64x136 LDS ----
  bf16* Cg = (bf16*)((MODE == 0 && blockIdx.z != 0) ? C1 : C0);
#pragma unroll
  for (int h = 0; h < 2; ++h) {
    if (wm == h) {
#pragma unroll
      for (int mt = 0; mt < 4; ++mt)
#pragma unroll
        for (int nt = 0; nt < 2; ++nt) {
          const float bb = (MODE == 0) ? 0.f : bias[n0 + wn * 32 + nt * 16 + l15];
#pragma unroll
          for (int r = 0; r < 4; ++r) {
            float v = acc[mt][nt][r] + bb;
            if (MODE == 2) v = gelu_fast(v);
            smem[(mt * 16 + quad * 4 + r) * 136 + wn * 32 + nt * 16 + l15] = (bf16)v;
          }
        }
    }
    __syncthreads();
    {
      const int row = tid >> 3;                    // 0..63
#pragma unroll
      for (int p = 0; p < 2; ++p) {
        const int chunk = (tid & 7) + p * 8;       // 0..15
        bf16x8 vv = *(const bf16x8*)&smem[row * 136 + chunk * 8];
        *(bf16x8*)&Cg[(m0 + h * 64 + row) * N + n0 + chunk * 8] = vv;
      }
    }
    __syncthreads();
  }
}

// ----------------------------- attention -----------------------------------
__global__ __launch_bounds__(256) void attn_kernel(
    const bf16* __restrict__ qkv, const bf16* __restrict__ vt,
    const int* __restrict__ amask, bf16* __restrict__ attn_out) {
  constexpr int S = 4096, HID3 = 2304;
  __shared__ bf16 Ss[64 * 328];
  __shared__ bf16 Ts[64 * 64];
  __shared__ float redm[64], reds[64];

  const int x = blockIdx.x, q0 = x * 64, h = blockIdx.y, b = blockIdx.z;
  const int tid = threadIdx.x, wave = tid >> 6, lane = tid & 63;
  const int l15 = lane & 15, quad = lane >> 4;
  const int rowoff = tid >> 3;
  const int sc_sw = (tid & 7) ^ (rowoff & 7);
  const int fsw = l15 & 7;
  const int t_lo = (x < 2) ? (2 - x) : 0;
  const int t_hi = (x > 61) ? (66 - x) : 5;

  const bf16* Qb = qkv + (long)b * S * HID3 + h * 64;
  const bf16* Kb = Qb + 768;
  const bf16* Vt_bh = vt + ((long)(b * 12 + h)) * 64 * 4096;

  bf16x8 qf[2];
  {
    const long qrow = q0 + wave * 16 + l15;
    qf[0] = *(const bf16x8*)&Qb[qrow * HID3 + quad * 8];
    qf[1] = *(const bf16x8*)&Qb[qrow * HID3 + 32 + quad * 8];
  }

  float mrow[4] = {-3e38f, -3e38f, -3e38f, -3e38f};

  // ---- Phase A: scores ----
  for (int t = t_lo; t < t_hi; ++t) {
    const int j0 = (x - 2 + t) * 64;
    __syncthreads();
#pragma unroll
    for (int p = 0; p < 2; ++p) {
      const int key = p * 32 + rowoff;
      gld_lds16(Kb + (long)(j0 + key) * HID3 + sc_sw * 8, &Ts[p * 2048 + wave * 512]);
    }
    __syncthreads();
    floatx4 sacc[4] = {};
#pragma unroll
    for (int kk = 0; kk < 2; ++kk) {
      const int ch = ((kk * 4 + quad) ^ fsw) * 8;
#pragma unroll
      for (int nt = 0; nt < 4; ++nt) {
        bf16x8 kf = *(const bf16x8*)&Ts[(nt * 16 + l15) * 64 + ch];
        sacc[nt] = MFMA16(qf[kk], kf, sacc[nt]);
      }
    }
#pragma unroll
    for (int nt = 0; nt < 4; ++nt) {
      const int jj = t * 64 + nt * 16 + l15;
      const int j = j0 + nt * 16 + l15;
      const bool jv = (amask[b * S + j] != 0);
#pragma unroll
      for (int r = 0; r < 4; ++r) {
        const int qi = wave * 16 + quad * 4 + r;
        const bool ok = jv && (jj >= qi) && (jj <= qi + 256);
        const float sv = ok ? sacc[nt][r] * 0.125f : -1e9f;
        mrow[r] = fmaxf(mrow[r], sv);
        Ss[(wave * 16 + quad * 4 + r) * 328 + jj] = (bf16)sv;
      }
    }
  }
#pragma unroll
  for (int off = 1; off < 16; off <<= 1)
#pragma unroll
    for (int r = 0; r < 4; ++r)
      mrow[r] = fmaxf(mrow[r], __shfl_xor(mrow[r], off, 64));
  if (l15 == 0) {
#pragma unroll
    for (int r = 0; r < 4; ++r) redm[wave * 16 + quad * 4 + r] = mrow[r];
  }
  __syncthreads();

  // ---- Phase B: softmax pass (rows re-owned by l15, chunks by quad) ----
  {
    const int row = wave * 16 + l15;
    const float mx = redm[row];
    float sum = 0.f;
    for (int c = t_lo * 8 + quad; c < t_hi * 8; c += 4) {
      bf16x8 pv = *(const bf16x8*)&Ss[row * 328 + c * 8];
#pragma unroll
      for (int u = 0; u < 8; ++u) {
        const float p = __expf((float)pv[u] - mx);
        sum += p;
        pv[u] = (bf16)p;
      }
      *(bf16x8*)&Ss[row * 328 + c * 8] = pv;
    }
    sum += __shfl_xor(sum, 16, 64);
    sum += __shfl_xor(sum, 32, 64);
    if (quad == 0) reds[row] = sum;
  }
  __syncthreads();

  // ---- Phase C: P @ V with pre-transposed V ----
  floatx4 oacc[4] = {};
  for (int t = t_lo; t < t_hi; ++t) {
    const int j0 = (x - 2 + t) * 64;
    __syncthreads();
#pragma unroll
    for (int p = 0; p < 2; ++p) {
      const int d = p * 32 + rowoff;
      gld_lds16(Vt_bh + (long)d * 4096 + j0 + sc_sw * 8, &Ts[p * 2048 + wave * 512]);
    }
    __syncthreads();
#pragma unroll
    for (int kk = 0; kk < 2; ++kk) {
      const int ko = kk * 32 + quad * 8;
      const int ch = ((kk * 4 + quad) ^ fsw) * 8;
      bf16x8 pf = *(const bf16x8*)&Ss[(wave * 16 + l15) * 328 + t * 64 + ko];
#pragma unroll
      for (int nt = 0; nt < 4; ++nt) {
        bf16x8 vf = *(const bf16x8*)&Ts[(nt * 16 + l15) * 64 + ch];
        oacc[nt] = MFMA16(pf, vf, oacc[nt]);
      }
    }
  }

  float inv[4];
#pragma unroll
  for (int r = 0; r < 4; ++r) inv[r] = fast_rcp(reds[wave * 16 + quad * 4 + r]);
  const long orow = (long)b * S + q0 + wave * 16 + quad * 4;
#pragma unroll
  for (int nt = 0; nt < 4; ++nt)
#pragma unroll
    for (int r = 0; r < 4; ++r)
      attn_out[(orow + r) * 768 + h * 64 + nt * 16 + l15] =
          (bf16)(oacc[nt][r] * inv[r]);
}

// ------------------------------ final head ---------------------------------
__global__ __launch_bounds__(256) void final_kernel(
    const float* __restrict__ h32, const float* __restrict__ Wp,
    const float* __restrict__ bp, float* __restrict__ out) {
  const int wave = threadIdx.x >> 6, lane = threadIdx.x & 63;
  const long tok = (long)blockIdx.x * 4 + wave;
  float s = 0.f;
#pragma unroll
  for (int i = 0; i < 12; ++i) {
    const int c = lane + i * 64;
    s += h32[tok * 768 + c] * Wp[c];
  }
#pragma unroll
  for (int off = 32; off > 0; off >>= 1) s += __shfl_down(s, off, 64);
  if (lane == 0) out[tok] = fast_rcp(1.f + __expf(-(s + bp[0])));
}

// ------------------------------ launcher -----------------------------------
extern "C" void kernel_launch(void* const* d_in, const int* in_sizes, int n_in,
                              void* d_out, int out_size, void* d_ws, size_t ws_size,
                              hipStream_t stream) {
  const float* emb   = (const float*)d_in[0];
  const int*   amask = (const int*)d_in[1];
  const float* pos   = (const float*)d_in[2];
  const float* tok   = (const float*)d_in[3];
  const float* elng  = (const float*)d_in[4];
  const float* elnb  = (const float*)d_in[5];
  const float* Wq = (const float*)d_in[6];   const float* bq = (const float*)d_in[7];
  const float* Wk = (const float*)d_in[8];   const float* bk = (const float*)d_in[9];
  const float* Wv = (const float*)d_in[10];  const float* bv = (const float*)d_in[11];
  const float* Wo = (const float*)d_in[12];  const float* bo = (const float*)d_in[13];
  const float* ln1g = (const float*)d_in[14]; const float* ln1b = (const float*)d_in[15];
  const float* Wi = (const float*)d_in[16];  const float* bi = (const float*)d_in[17];
  const float* Wf = (const float*)d_in[18];  const float* bfb = (const float*)d_in[19];
  const float* ln2g = (const float*)d_in[20]; const float* ln2b = (const float*)d_in[21];
  const float* Wp = (const float*)d_in[22];  const float* bp = (const float*)d_in[23];
  float* out = (float*)d_out;

  char* ws = (char*)d_ws;
  bf16*  WTqkv = (bf16*)(ws + OFF_WTQKV);
  bf16*  WTo   = (bf16*)(ws + OFF_WTO);
  bf16*  WTi   = (bf16*)(ws + OFF_WTI);
  bf16*  WTf   = (bf16*)(ws + OFF_WTF);
  float* bqkv  = (float*)(ws + OFF_BQKV);
  float* h32   = (float*)(ws + OFF_H32);
  bf16*  hbf   = (bf16*)(ws + OFF_HBF);
  bf16*  qkvb  = (bf16*)(ws + OFF_QKV);
  bf16*  part1 = (bf16*)(ws + OFF_QKV);    // bf16 overlay; qkvb dead after attn
  bf16*  attnb = (bf16*)(ws + OFF_ATTN);
  bf16*  part0 = (bf16*)(ws + OFF_TMP);
  bf16*  vtb   = (bf16*)(ws + OFF_TMP);    // Vt overlay; part0 dead during attn
  bf16*  ffn1  = (bf16*)(ws + OFF_FFN1);

  const dim3 tb(32, 8, 1);
  transpose_cast<<<dim3(24, 24, 4), tb, 0, stream>>>(Wq, WTqkv,               768, 768,  (long)768 * 768,  (long)2304 * 768);
  transpose_cast<<<dim3(24, 24, 4), tb, 0, stream>>>(Wk, WTqkv + 768 * 768,   768, 768,  (long)768 * 768,  (long)2304 * 768);
  transpose_cast<<<dim3(24, 24, 4), tb, 0, stream>>>(Wv, WTqkv + 1536 * 768,  768, 768,  (long)768 * 768,  (long)2304 * 768);
  transpose_cast<<<dim3(24, 24, 4), tb, 0, stream>>>(Wo, WTo,                 768, 768,  (long)768 * 768,  (long)768 * 768);
  transpose_cast<<<dim3(96, 24, 4), tb, 0, stream>>>(Wi, WTi,                 768, 3072, (long)768 * 3072, (long)3072 * 768);
  transpose_cast<<<dim3(24, 96, 4), tb, 0, stream>>>(Wf, WTf,                 3072, 768, (long)3072 * 768, (long)768 * 3072);
  bias_concat<<<36, 256, 0, stream>>>(bq, bk, bv, bqkv);

  embed_ln_kernel<<<8192, 256, 0, stream>>>(emb, pos, tok, elng, elnb, h32, hbf);

  for (int l = 0; l < 4; ++l) {
    gemm_kernel<1, 2304, 768><<<dim3(64, 18, 1), 512, 0, stream>>>(
        hbf, WTqkv + (size_t)l * 2304 * 768, bqkv + l * 2304, qkvb, nullptr, vtb, 768);
    attn_kernel<<<dim3(64, 12, 2), 256, 0, stream>>>(qkvb, vtb, amask, attnb);
    gemm_kernel<0, 768, 768><<<dim3(64, 6, 2), 512, 0, stream>>>(
        attnb, WTo + (size_t)l * 768 * 768, nullptr, part0, part1, nullptr, 384);
    add_ln_kernel<<<8192, 256, 0, stream>>>(h32, part0, part1, bo + l * 768,
                                            ln1g + l * 768, ln1b + l * 768, hbf);
    gemm_kernel<2, 3072, 768><<<dim3(64, 24, 1), 512, 0, stream>>>(
        hbf, WTi + (size_t)l * 3072 * 768, bi + l * 3072, ffn1, nullptr, nullptr, 768);
    gemm_kernel<0, 768, 3072><<<dim3(64, 6, 2), 512, 0, stream>>>(
        ffn1, WTf + (size_t)l * 768 * 3072, nullptr, part0, part1, nullptr, 1536);
    add_ln_kernel<<<8192, 256, 0, stream>>>(h32, part0, part1, bfb + l * 768,
                                            ln2g + l * 768, ln2b + l * 768, hbf);
  }

  final_kernel<<<2048, 256, 0, stream>>>(h32, Wp, bp, out);
}